// Round 3
// baseline (387.911 us; speedup 1.0000x reference)
//
#include <hip/hip_runtime.h>
#include <hip/hip_cooperative_groups.h>
#include <math.h>

namespace cg = cooperative_groups;

// Problem constants (fixed by setup_inputs): N_ref=128, N_src=128, D=256.
#define NREF 128
#define NSRC 128
#define DIM  256
#define EPS  1e-5f

// ---------------------------------------------------------------------------
// Single cooperative kernel, 256 blocks x 512 threads (1 block/CU).
// Phase 1 (all blocks)  : side computation  -> arrs[0..1024)      (ws)
// Phase 2 (all blocks)  : ranks + geo + y1  -> y1[0..256)         (ws+1024)
// Phase 3 (blocks 0-127): GN1 + relu + y2   -> y2[0..128)         (ws+1280)
// Phase 4 (block 0)     : GN2 + relu + W3   -> out[0..2)
// All float reduction trees identical to the round-2 kernels (absmax 0.0).
// grid.sync() replaces 3 kernel-launch gaps; __threadfence() gives the
// device-scope release/acquire the dispatch boundaries used to provide.
// ---------------------------------------------------------------------------
__global__ __launch_bounds__(512) void fused_kernel(
    const float* __restrict__ points_c,
    const float* __restrict__ trans,
    const float* __restrict__ ref_feats,
    const float* __restrict__ src_feats,
    const float* __restrict__ W1, const float* __restrict__ b1,
    const float* __restrict__ g1, const float* __restrict__ bt1,
    const float* __restrict__ W2, const float* __restrict__ b2,
    const float* __restrict__ g2, const float* __restrict__ bt2,
    const float* __restrict__ W3, const float* __restrict__ b3,
    float* __restrict__ arrs,     // ws: [0,1024) arrs, [1024,1280) y1, [1280,1408) y2
    float* __restrict__ out)
{
    cg::grid_group grid = cg::this_grid();

    // phase-1 LDS
    __shared__ float px[256], py[256], pz[256], nsq[256];
    __shared__ float wred[12];
    __shared__ float red[4];
    __shared__ float featLds[128];
    __shared__ float cvD[8]; __shared__ int ciD[8];
    __shared__ float cvF[8]; __shared__ int ciF[8];
    // phase-2 LDS
    __shared__ __align__(16) float arrD[256], arrFS[256], arrMF[256], arrMD[256];
    __shared__ __align__(16) float geoLds[512];
    // phase-3 LDS
    __shared__ __align__(16) float y1s[256];
    __shared__ float stats[16];
    // phase-4 LDS
    __shared__ float y2s[128], h2s[128];

    float* __restrict__ y1g = arrs + 1024;
    float* __restrict__ y2g = arrs + 1280;

    const int t = threadIdx.x;
    const int w = t >> 6, l = t & 63;

    // =======================================================================
    // Phase 1: side computation (round-2 side_kernel body, verbatim)
    // =======================================================================
    {
        const int b = blockIdx.x;
        const bool isRow = (b < NREF);
        const int  me    = isRow ? b : (b - NREF);

        float x = 0.f, y = 0.f, z = 0.f;
        if (t < 256) {
            x = points_c[3 * t + 0];
            y = points_c[3 * t + 1];
            z = points_c[3 * t + 2];
            if (t >= NREF) {
                float nx = trans[0] * x + trans[1] * y + trans[2]  * z + trans[3];
                float ny = trans[4] * x + trans[5] * y + trans[6]  * z + trans[7];
                float nz = trans[8] * x + trans[9] * y + trans[10] * z + trans[11];
                x = nx; y = ny; z = nz;
            }
        }

        // feat dots: 8 waves x 16 scanned indices, 2-dot ILP
        const float* __restrict__ myrow = (isRow ? ref_feats : src_feats) + me * DIM;
        const float4* __restrict__ other = (const float4*)(isRow ? src_feats : ref_feats);
        const float4 r = ((const float4*)myrow)[l];

        float bfv = -2.f; int bfi = 0;
        for (int m = 0; m < 16; m += 2) {
            const int j0 = w * 16 + m, j1 = j0 + 1;
            const float4 a0 = other[j0 * 64 + l];
            const float4 a1 = other[j1 * 64 + l];
            float acc0 = a0.x * r.x + a0.y * r.y + a0.z * r.z + a0.w * r.w;
            float acc1 = a1.x * r.x + a1.y * r.y + a1.z * r.z + a1.w * r.w;
            for (int off = 32; off >= 1; off >>= 1) {
                acc0 += __shfl_xor(acc0, off);
                acc1 += __shfl_xor(acc1, off);
            }
            if (l == 0) { featLds[j0] = acc0; featLds[j1] = acc1; }
            if (acc0 > bfv) { bfv = acc0; bfi = j0; }
            if (acc1 > bfv) { bfv = acc1; bfi = j1; }
        }
        if (l == 0) { cvF[w] = bfv; ciF[w] = bfi; }

        // point normalization
        if (t < 256) {
            float sx = x, sy = y, sz = z;
            for (int off = 32; off >= 1; off >>= 1) {
                sx += __shfl_down(sx, off);
                sy += __shfl_down(sy, off);
                sz += __shfl_down(sz, off);
            }
            if (l == 0) { wred[w] = sx; wred[4 + w] = sy; wred[8 + w] = sz; }
        }
        __syncthreads();
        if (t == 0) {
            red[0] = (wred[0] + wred[1] + wred[2] + wred[3]) * (1.0f / 256.0f);
            red[1] = (wred[4] + wred[5] + wred[6] + wred[7]) * (1.0f / 256.0f);
            red[2] = (wred[8] + wred[9] + wred[10] + wred[11]) * (1.0f / 256.0f);
        }
        __syncthreads();
        if (t < 256) {
            x -= red[0]; y -= red[1]; z -= red[2];
            float n = x * x + y * y + z * z;
            float mx = n;
            for (int off = 32; off >= 1; off >>= 1)
                mx = fmaxf(mx, __shfl_down(mx, off));
            if (l == 0) wred[w] = mx;
        }
        __syncthreads();
        if (t == 0)
            red[3] = 1.0f / sqrtf(fmaxf(fmaxf(wred[0], wred[1]), fmaxf(wred[2], wred[3])));
        __syncthreads();
        if (t < 256) {
            const float inv = red[3];
            x *= inv; y *= inv; z *= inv;
            px[t] = x; py[t] = y; pz[t] = z;
            nsq[t] = x * x + y * y + z * z;
        }
        __syncthreads();

        // dist argmax scan
        float bdv = -1.f; int bdi = 0;
        for (int m = 0; m < 16; ++m) {
            const int jj = w * 16 + m;
            const int i = isRow ? me : jj;
            const int j = isRow ? jj : me;
            float d = nsq[i] + nsq[128 + j]
                    - 2.0f * (px[i] * px[128 + j] + py[i] * py[128 + j] + pz[i] * pz[128 + j]);
            d = fmaxf(d, 0.f);
            const float v = expf(-d);
            if (v > bdv) { bdv = v; bdi = jj; }
        }
        if (l == 0) { cvD[w] = bdv; ciD[w] = bdi; }
        __syncthreads();

        // combine + gathers
        if (t == 0) {
            float bv = -1.f; int bi = 0;
            for (int q = 0; q < 8; ++q)
                if (cvD[q] > bv) { bv = cvD[q]; bi = ciD[q]; }
            float fv = -2.f; int fi = 0;
            for (int q = 0; q < 8; ++q)
                if (cvF[q] > fv) { fv = cvF[q]; fi = ciF[q]; }
            const float fscore = featLds[bi];
            const int i = isRow ? me : fi;
            const int j = isRow ? fi : me;
            float d = nsq[i] + nsq[128 + j]
                    - 2.0f * (px[i] * px[128 + j] + py[i] * py[128 + j] + pz[i] * pz[128 + j]);
            d = fmaxf(d, 0.f);
            const float mdist = expf(-d);
            const int gi = isRow ? me : NREF + me;
            arrs[gi]       = bv;        // min_dist
            arrs[256 + gi] = fscore;    // feat_score
            arrs[512 + gi] = fv;        // match_feat
            arrs[768 + gi] = mdist;     // match_dist
        }
    }

    __threadfence();
    grid.sync();
    __threadfence();

    // =======================================================================
    // Phase 2: ranks + geo + y1[c], c = blockIdx.x (round-2 mlp1 body)
    // =======================================================================
    {
        const int c = blockIdx.x;
        if (t < 256) {
            arrD[t]  = arrs[t];
            arrFS[t] = arrs[256 + t];
            arrMF[t] = arrs[512 + t];
            arrMD[t] = arrs[768 + t];
        }
        __syncthreads();
        if (t < 256) {
            const float vD = arrD[t];
            const float vF = arrMF[t];
            int rD = 0, rF = 0;
            for (int jb = 0; jb < 64; ++jb) {
                const float4 uD = ((const float4*)arrD)[jb];
                const float4 uF = ((const float4*)arrMF)[jb];
                const int j0 = 4 * jb;
                rD += (uD.x > vD) || (uD.x == vD && (j0 + 0) < t);
                rD += (uD.y > vD) || (uD.y == vD && (j0 + 1) < t);
                rD += (uD.z > vD) || (uD.z == vD && (j0 + 2) < t);
                rD += (uD.w > vD) || (uD.w == vD && (j0 + 3) < t);
                rF += (uF.x > vF) || (uF.x == vF && (j0 + 0) < t);
                rF += (uF.y > vF) || (uF.y == vF && (j0 + 1) < t);
                rF += (uF.z > vF) || (uF.z == vF && (j0 + 2) < t);
                rF += (uF.w > vF) || (uF.w == vF && (j0 + 3) < t);
            }
            geoLds[rD]       = vD * arrFS[t];
            geoLds[256 + rF] = arrMD[t] * vF;
        }
        __syncthreads();
        if (t < 64) {
            const float4 ga = ((const float4*)geoLds)[t];
            const float4 gb = ((const float4*)geoLds)[64 + t];
            const float4* __restrict__ wrow = (const float4*)(W1 + c * 512);
            const float4 a = wrow[t];
            const float4 b = wrow[64 + t];
            float acc = a.x * ga.x + a.y * ga.y + a.z * ga.z + a.w * ga.w
                      + b.x * gb.x + b.y * gb.y + b.z * gb.z + b.w * gb.w;
            acc += __shfl_down(acc, 32);
            acc += __shfl_down(acc, 16);
            acc += __shfl_down(acc, 8);
            acc += __shfl_down(acc, 4);
            acc += __shfl_down(acc, 2);
            acc += __shfl_down(acc, 1);
            if (t == 0) y1g[c] = acc + b1[c];
        }
    }

    __threadfence();
    grid.sync();
    __threadfence();

    // =======================================================================
    // Phase 3: GN1 + relu + y2[c], blocks 0..127 (round-2 mlp2 body)
    // =======================================================================
    if (blockIdx.x < 128) {
        const int c = blockIdx.x;
        if (t < 64) ((float4*)y1s)[t] = ((const float4*)y1g)[t];
        __syncthreads();
        if (t < 8) {
            float s = 0.f;
            for (int k = 0; k < 32; ++k) s += y1s[(t << 5) + k];
            const float mean = s * (1.0f / 32.0f);
            float q = 0.f;
            for (int k = 0; k < 32; ++k) { const float d = y1s[(t << 5) + k] - mean; q += d * d; }
            const float var = q * (1.0f / 32.0f);
            stats[t] = mean;
            stats[8 + t] = rsqrtf(var + EPS);
        }
        __syncthreads();
        if (t < 64) {
            const float4 gg = ((const float4*)g1)[t];
            const float4 bb = ((const float4*)bt1)[t];
            const int g = t >> 3;
            const float mean = stats[g], inv = stats[8 + g];
            const float4 yv = ((const float4*)y1s)[t];
            float4 h;
            h.x = fmaxf((yv.x - mean) * inv * gg.x + bb.x, 0.f);
            h.y = fmaxf((yv.y - mean) * inv * gg.y + bb.y, 0.f);
            h.z = fmaxf((yv.z - mean) * inv * gg.z + bb.z, 0.f);
            h.w = fmaxf((yv.w - mean) * inv * gg.w + bb.w, 0.f);
            const float4 wv = ((const float4*)(W2 + c * 256))[t];
            float acc = wv.x * h.x + wv.y * h.y + wv.z * h.z + wv.w * h.w;
            acc += __shfl_down(acc, 32);
            acc += __shfl_down(acc, 16);
            acc += __shfl_down(acc, 8);
            acc += __shfl_down(acc, 4);
            acc += __shfl_down(acc, 2);
            acc += __shfl_down(acc, 1);
            if (t == 0) y2g[c] = acc + b2[c];
        }
    }

    __threadfence();
    grid.sync();
    __threadfence();

    // =======================================================================
    // Phase 4: GN2 + relu + W3, block 0 (round-2 final body)
    // =======================================================================
    if (blockIdx.x == 0) {
        if (t < 128) y2s[t] = y2g[t];
        __syncthreads();
        if (t < 128) {
            const int g = t >> 4;
            float s = 0.f;
            for (int k = 0; k < 16; ++k) s += y2s[(g << 4) + k];
            const float mean = s * (1.0f / 16.0f);
            float q = 0.f;
            for (int k = 0; k < 16; ++k) { const float d = y2s[(g << 4) + k] - mean; q += d * d; }
            const float var = q * (1.0f / 16.0f);
            const float xn = (y2s[t] - mean) * rsqrtf(var + EPS);
            h2s[t] = fmaxf(xn * g2[t] + bt2[t], 0.f);
        }
        __syncthreads();
        if (t < 128) {
            const int wave = t >> 6, lane = t & 63;
            float acc = W3[wave * 128 + lane] * h2s[lane]
                      + W3[wave * 128 + 64 + lane] * h2s[64 + lane];
            acc += __shfl_down(acc, 32);
            acc += __shfl_down(acc, 16);
            acc += __shfl_down(acc, 8);
            acc += __shfl_down(acc, 4);
            acc += __shfl_down(acc, 2);
            acc += __shfl_down(acc, 1);
            if (lane == 0) out[wave] = acc + b3[wave];
        }
    }
}

// ---------------------------------------------------------------------------
extern "C" void kernel_launch(void* const* d_in, const int* in_sizes, int n_in,
                              void* d_out, int out_size, void* d_ws, size_t ws_size,
                              hipStream_t stream)
{
    const float* points_c  = (const float*)d_in[0];
    const float* ref_feats = (const float*)d_in[1];
    const float* src_feats = (const float*)d_in[2];
    const float* trans     = (const float*)d_in[3];
    const float* W1  = (const float*)d_in[4];
    const float* b1  = (const float*)d_in[5];
    const float* g1  = (const float*)d_in[6];
    const float* bt1 = (const float*)d_in[7];
    const float* W2  = (const float*)d_in[8];
    const float* b2  = (const float*)d_in[9];
    const float* g2  = (const float*)d_in[10];
    const float* bt2 = (const float*)d_in[11];
    const float* W3  = (const float*)d_in[12];
    const float* b3  = (const float*)d_in[13];
    // d_in[14] = ref_length (int, == 128): fixed at compile time.

    float* arrs = (float*)d_ws;          // [0,1024) arrs, [1024,1280) y1, [1280,1408) y2
    float* outp = (float*)d_out;

    void* args[] = {
        (void*)&points_c, (void*)&trans, (void*)&ref_feats, (void*)&src_feats,
        (void*)&W1, (void*)&b1, (void*)&g1, (void*)&bt1,
        (void*)&W2, (void*)&b2, (void*)&g2, (void*)&bt2,
        (void*)&W3, (void*)&b3,
        (void*)&arrs, (void*)&outp
    };
    hipLaunchCooperativeKernel((const void*)fused_kernel,
                               dim3(256), dim3(512), args, 0, stream);
}

// Round 4
// 108.869 us; speedup vs baseline: 3.5631x; 3.5631x over previous
//
#include <hip/hip_runtime.h>
#include <math.h>

// Problem constants (fixed by setup_inputs): N_ref=128, N_src=128, D=256.
#define NREF 128
#define NSRC 128
#define DIM  256
#define EPS  1e-5f

// ---------------------------------------------------------------------------
// K1: one block per output element of the concatenated 256-vectors.
//   b in [0,128)   -> "row" block, owns ref index i=b       (scans over j)
//   b in [128,256) -> "col" block, owns src index j=b-128   (scans over i)
// Bitwise-verified in rounds 1-3 (absmax 0.0). Changes this round:
//   - all 16 feat float4 loads preissued (one latency burst, same tree order)
//   - warms W1 row b into L2/L3 for mlp1 (asm-sink keeps loads live)
// ---------------------------------------------------------------------------
__global__ __launch_bounds__(512) void side_kernel(
    const float* __restrict__ points_c,
    const float* __restrict__ trans,
    const float* __restrict__ ref_feats,
    const float* __restrict__ src_feats,
    const float* __restrict__ W1,
    float* __restrict__ arrs)   // [0,256)=min_dist [256,512)=feat_score
                                // [512,768)=match_feat [768,1024)=match_dist
{
    __shared__ float px[256], py[256], pz[256], nsq[256];
    __shared__ float wred[12];
    __shared__ float red[4];
    __shared__ float featLds[128];
    __shared__ float cvD[8]; __shared__ int ciD[8];
    __shared__ float cvF[8]; __shared__ int ciF[8];

    const int b = blockIdx.x;
    const int t = threadIdx.x;
    const int w = t >> 6, l = t & 63;

    const bool isRow = (b < NREF);
    const int  me    = isRow ? b : (b - NREF);

    // ---- W1 warm: row b (2 KB), issued now, sunk at kernel end ----
    const float4 w1warm = ((const float4*)(W1 + (size_t)b * 512))[t & 127];

    // ---- load my point ----
    float x = 0.f, y = 0.f, z = 0.f;
    if (t < 256) {
        x = points_c[3 * t + 0];
        y = points_c[3 * t + 1];
        z = points_c[3 * t + 2];
        if (t >= NREF) {
            float nx = trans[0] * x + trans[1] * y + trans[2]  * z + trans[3];
            float ny = trans[4] * x + trans[5] * y + trans[6]  * z + trans[7];
            float nz = trans[8] * x + trans[9] * y + trans[10] * z + trans[11];
            x = nx; y = ny; z = nz;
        }
    }

    // ---- feat dots: preload all 16 float4s, then 8x 2-ILP shuffle trees ----
    const float* __restrict__ myrow = (isRow ? ref_feats : src_feats) + me * DIM;
    const float4* __restrict__ other = (const float4*)(isRow ? src_feats : ref_feats);
    const float4 r = ((const float4*)myrow)[l];

    float4 av[16];
    #pragma unroll
    for (int m = 0; m < 16; ++m)
        av[m] = other[(w * 16 + m) * 64 + l];

    float bfv = -2.f; int bfi = 0;
    #pragma unroll
    for (int m = 0; m < 16; m += 2) {
        const int j0 = w * 16 + m, j1 = j0 + 1;
        float acc0 = av[m].x * r.x + av[m].y * r.y + av[m].z * r.z + av[m].w * r.w;
        float acc1 = av[m+1].x * r.x + av[m+1].y * r.y + av[m+1].z * r.z + av[m+1].w * r.w;
        for (int off = 32; off >= 1; off >>= 1) {
            acc0 += __shfl_xor(acc0, off);
            acc1 += __shfl_xor(acc1, off);
        }
        if (l == 0) { featLds[j0] = acc0; featLds[j1] = acc1; }
        if (acc0 > bfv) { bfv = acc0; bfi = j0; }
        if (acc1 > bfv) { bfv = acc1; bfi = j1; }
    }
    if (l == 0) { cvF[w] = bfv; ciF[w] = bfi; }

    // ---- point normalization (same reduction trees as round 0) ----
    if (t < 256) {
        float sx = x, sy = y, sz = z;
        for (int off = 32; off >= 1; off >>= 1) {
            sx += __shfl_down(sx, off);
            sy += __shfl_down(sy, off);
            sz += __shfl_down(sz, off);
        }
        if (l == 0) { wred[w] = sx; wred[4 + w] = sy; wred[8 + w] = sz; }
    }
    __syncthreads();
    if (t == 0) {
        red[0] = (wred[0] + wred[1] + wred[2] + wred[3]) * (1.0f / 256.0f);
        red[1] = (wred[4] + wred[5] + wred[6] + wred[7]) * (1.0f / 256.0f);
        red[2] = (wred[8] + wred[9] + wred[10] + wred[11]) * (1.0f / 256.0f);
    }
    __syncthreads();
    if (t < 256) {
        x -= red[0]; y -= red[1]; z -= red[2];
        float n = x * x + y * y + z * z;
        float mx = n;
        for (int off = 32; off >= 1; off >>= 1)
            mx = fmaxf(mx, __shfl_down(mx, off));
        if (l == 0) wred[w] = mx;
    }
    __syncthreads();
    if (t == 0)
        red[3] = 1.0f / sqrtf(fmaxf(fmaxf(wred[0], wred[1]), fmaxf(wred[2], wred[3])));
    __syncthreads();
    if (t < 256) {
        const float inv = red[3];
        x *= inv; y *= inv; z *= inv;
        px[t] = x; py[t] = y; pz[t] = z;
        nsq[t] = x * x + y * y + z * z;
    }
    __syncthreads();

    // ---- dist argmax scan: 8 waves x 16, all lanes redundant (identical) ----
    float bdv = -1.f; int bdi = 0;
    for (int m = 0; m < 16; ++m) {
        const int jj = w * 16 + m;
        const int i = isRow ? me : jj;
        const int j = isRow ? jj : me;
        float d = nsq[i] + nsq[128 + j]
                - 2.0f * (px[i] * px[128 + j] + py[i] * py[128 + j] + pz[i] * pz[128 + j]);
        d = fmaxf(d, 0.f);
        const float v = expf(-d);
        if (v > bdv) { bdv = v; bdi = jj; }
    }
    if (l == 0) { cvD[w] = bdv; ciD[w] = bdi; }
    __syncthreads();

    // ---- combine chunks (ascending wave order, strict >) + gathers ----
    if (t == 0) {
        float bv = -1.f; int bi = 0;
        for (int q = 0; q < 8; ++q)
            if (cvD[q] > bv) { bv = cvD[q]; bi = ciD[q]; }
        float fv = -2.f; int fi = 0;
        for (int q = 0; q < 8; ++q)
            if (cvF[q] > fv) { fv = cvF[q]; fi = ciF[q]; }
        const float fscore = featLds[bi];       // feat at dist-argmax
        const int i = isRow ? me : fi;          // dist at feat-argmax
        const int j = isRow ? fi : me;
        float d = nsq[i] + nsq[128 + j]
                - 2.0f * (px[i] * px[128 + j] + py[i] * py[128 + j] + pz[i] * pz[128 + j]);
        d = fmaxf(d, 0.f);
        const float mdist = expf(-d);
        const int gi = isRow ? me : NREF + me;
        arrs[gi]       = bv;        // min_dist
        arrs[256 + gi] = fscore;    // feat_score
        arrs[512 + gi] = fv;        // match_feat
        arrs[768 + gi] = mdist;     // match_dist
    }

    // keep the W1 warm loads live (rule #17) — no-op, long since retired
    asm volatile("" :: "v"(w1warm.x), "v"(w1warm.y), "v"(w1warm.z), "v"(w1warm.w));
}

// ---------------------------------------------------------------------------
// K2: y1[c] for c = blockIdx.x. 256 blocks x 256 threads.
// Round-2 body verbatim (bitwise-verified) + cache warming for the tail:
//   blocks 0..127 warm W2 row c; block 1 warms W3/g2/bt2/b2; block 0 warms
//   g1/bt1 (tail reads them).
// ---------------------------------------------------------------------------
__global__ __launch_bounds__(256) void mlp1_kernel(
    const float* __restrict__ arrs,
    const float* __restrict__ W1, const float* __restrict__ b1,
    const float* __restrict__ W2,
    const float* __restrict__ g1, const float* __restrict__ bt1,
    const float* __restrict__ W3, const float* __restrict__ b2,
    const float* __restrict__ g2, const float* __restrict__ bt2,
    float* __restrict__ y1)
{
    __shared__ __align__(16) float arrD[256], arrFS[256], arrMF[256], arrMD[256];
    __shared__ __align__(16) float geoLds[512];
    const int c = blockIdx.x;
    const int t = threadIdx.x;

    // ---- warming loads (issued now, sunk at end) ----
    float4 warm = make_float4(0.f, 0.f, 0.f, 0.f);
    if (c < 128 && t < 64)
        warm = ((const float4*)(W2 + (size_t)c * 256))[t];
    else if (c == 128 && t < 64)
        warm = ((const float4*)W3)[t];                       // 256 floats
    else if (c == 129 && t < 64)
        warm = ((const float4*)g1)[t];                       // 256 floats
    else if (c == 130 && t < 64)
        warm = ((const float4*)bt1)[t];
    else if (c == 131 && t < 32)
        warm = ((const float4*)g2)[t];                       // 128 floats
    else if (c == 132 && t < 32)
        warm = ((const float4*)bt2)[t];
    else if (c == 133 && t < 32)
        warm = ((const float4*)b2)[t];

    const float b1c = b1[c];   // hoist bias load off the post-tree critical path

    arrD[t]  = arrs[t];
    arrFS[t] = arrs[256 + t];
    arrMF[t] = arrs[512 + t];
    arrMD[t] = arrs[768 + t];
    __syncthreads();

    // ---- stable descending ranks (== jnp.argsort(-v) scatter), 1 elem each
    {
        const float vD = arrD[t];
        const float vF = arrMF[t];
        int rD = 0, rF = 0;
        for (int jb = 0; jb < 64; ++jb) {
            const float4 uD = ((const float4*)arrD)[jb];
            const float4 uF = ((const float4*)arrMF)[jb];
            const int j0 = 4 * jb;
            rD += (uD.x > vD) || (uD.x == vD && (j0 + 0) < t);
            rD += (uD.y > vD) || (uD.y == vD && (j0 + 1) < t);
            rD += (uD.z > vD) || (uD.z == vD && (j0 + 2) < t);
            rD += (uD.w > vD) || (uD.w == vD && (j0 + 3) < t);
            rF += (uF.x > vF) || (uF.x == vF && (j0 + 0) < t);
            rF += (uF.y > vF) || (uF.y == vF && (j0 + 1) < t);
            rF += (uF.z > vF) || (uF.z == vF && (j0 + 2) < t);
            rF += (uF.w > vF) || (uF.w == vF && (j0 + 3) < t);
        }
        geoLds[rD]       = vD * arrFS[t];
        geoLds[256 + rF] = arrMD[t] * vF;
    }
    __syncthreads();

    // ---- exact round-0 mlp1 dot (wave 0 only) ----
    if (t < 64) {
        const float4 ga = ((const float4*)geoLds)[t];
        const float4 gb = ((const float4*)geoLds)[64 + t];
        const float4* __restrict__ wrow = (const float4*)(W1 + c * 512);
        const float4 a = wrow[t];
        const float4 b = wrow[64 + t];
        float acc = a.x * ga.x + a.y * ga.y + a.z * ga.z + a.w * ga.w
                  + b.x * gb.x + b.y * gb.y + b.z * gb.z + b.w * gb.w;
        acc += __shfl_down(acc, 32);
        acc += __shfl_down(acc, 16);
        acc += __shfl_down(acc, 8);
        acc += __shfl_down(acc, 4);
        acc += __shfl_down(acc, 2);
        acc += __shfl_down(acc, 1);
        if (t == 0) y1[c] = acc + b1c;
    }

    asm volatile("" :: "v"(warm.x), "v"(warm.y), "v"(warm.z), "v"(warm.w));
}

// ---------------------------------------------------------------------------
// K3: fused tail, 1 block x 512 threads.
//   GN1 + relu + y2 (8 waves x 16 channels, W2 rows preissued in one burst,
//   per-channel lane layout + shfl tree identical to round-2 mlp2)
//   then GN2 + relu + W3 (round-2 final body on LDS-resident y2).
// Replaces mlp2_kernel + final_kernel: one fewer dispatch gap.
// ---------------------------------------------------------------------------
__global__ __launch_bounds__(512) void tail_kernel(
    const float* __restrict__ y1,
    const float* __restrict__ g1, const float* __restrict__ bt1,
    const float* __restrict__ W2, const float* __restrict__ b2,
    const float* __restrict__ g2, const float* __restrict__ bt2,
    const float* __restrict__ W3, const float* __restrict__ b3,
    float* __restrict__ out)
{
    __shared__ __align__(16) float y1s[256];
    __shared__ float stats[16];   // mean[8], invstd[8]
    __shared__ __align__(16) float b2s[128];
    __shared__ float y2s[128], h2s[128];

    const int t = threadIdx.x;
    const int w = t >> 6, l = t & 63;

    // ---- preissue: W2 rows for my wave's 16 channels (one latency burst) ----
    float4 wv[16];
    #pragma unroll
    for (int m = 0; m < 16; ++m)
        wv[m] = ((const float4*)(W2 + (size_t)(w * 16 + m) * 256))[l];

    if (t < 64) ((float4*)y1s)[t] = ((const float4*)y1)[t];
    if (t < 32) ((float4*)b2s)[t] = ((const float4*)b2)[t];
    __syncthreads();

    // ---- GN1 stats (identical to round-2 mlp2's t<8 loop) ----
    if (t < 8) {
        float s = 0.f;
        for (int k = 0; k < 32; ++k) s += y1s[(t << 5) + k];
        const float mean = s * (1.0f / 32.0f);
        float q = 0.f;
        for (int k = 0; k < 32; ++k) { const float d = y1s[(t << 5) + k] - mean; q += d * d; }
        const float var = q * (1.0f / 32.0f);
        stats[t] = mean;
        stats[8 + t] = rsqrtf(var + EPS);
    }
    __syncthreads();

    // ---- h (post-GN relu float4 per lane) — identical to round-2 mlp2 ----
    {
        const float4 gg = ((const float4*)g1)[l];
        const float4 bb = ((const float4*)bt1)[l];
        const int g = l >> 3;
        const float mean = stats[g], inv = stats[8 + g];
        const float4 yv = ((const float4*)y1s)[l];
        float4 h;
        h.x = fmaxf((yv.x - mean) * inv * gg.x + bb.x, 0.f);
        h.y = fmaxf((yv.y - mean) * inv * gg.y + bb.y, 0.f);
        h.z = fmaxf((yv.z - mean) * inv * gg.z + bb.z, 0.f);
        h.w = fmaxf((yv.w - mean) * inv * gg.w + bb.w, 0.f);

        #pragma unroll
        for (int m = 0; m < 16; ++m) {
            float acc = wv[m].x * h.x + wv[m].y * h.y + wv[m].z * h.z + wv[m].w * h.w;
            acc += __shfl_down(acc, 32);
            acc += __shfl_down(acc, 16);
            acc += __shfl_down(acc, 8);
            acc += __shfl_down(acc, 4);
            acc += __shfl_down(acc, 2);
            acc += __shfl_down(acc, 1);
            if (l == 0) y2s[w * 16 + m] = acc + b2s[w * 16 + m];
        }
    }
    __syncthreads();

    // ---- GN2 + relu (round-2 final body, y2 already in LDS) ----
    if (t < 128) {
        const int g = t >> 4;
        float s = 0.f;
        for (int k = 0; k < 16; ++k) s += y2s[(g << 4) + k];
        const float mean = s * (1.0f / 16.0f);
        float q = 0.f;
        for (int k = 0; k < 16; ++k) { const float d = y2s[(g << 4) + k] - mean; q += d * d; }
        const float var = q * (1.0f / 16.0f);
        const float xn = (y2s[t] - mean) * rsqrtf(var + EPS);
        h2s[t] = fmaxf(xn * g2[t] + bt2[t], 0.f);
    }
    __syncthreads();
    if (t < 128) {
        const int wave = t >> 6, lane = t & 63;
        float acc = W3[wave * 128 + lane] * h2s[lane]
                  + W3[wave * 128 + 64 + lane] * h2s[64 + lane];
        acc += __shfl_down(acc, 32);
        acc += __shfl_down(acc, 16);
        acc += __shfl_down(acc, 8);
        acc += __shfl_down(acc, 4);
        acc += __shfl_down(acc, 2);
        acc += __shfl_down(acc, 1);
        if (lane == 0) out[wave] = acc + b3[wave];
    }
}

// ---------------------------------------------------------------------------
extern "C" void kernel_launch(void* const* d_in, const int* in_sizes, int n_in,
                              void* d_out, int out_size, void* d_ws, size_t ws_size,
                              hipStream_t stream)
{
    const float* points_c  = (const float*)d_in[0];
    const float* ref_feats = (const float*)d_in[1];
    const float* src_feats = (const float*)d_in[2];
    const float* trans     = (const float*)d_in[3];
    const float* W1  = (const float*)d_in[4];
    const float* b1  = (const float*)d_in[5];
    const float* g1  = (const float*)d_in[6];
    const float* bt1 = (const float*)d_in[7];
    const float* W2  = (const float*)d_in[8];
    const float* b2  = (const float*)d_in[9];
    const float* g2  = (const float*)d_in[10];
    const float* bt2 = (const float*)d_in[11];
    const float* W3  = (const float*)d_in[12];
    const float* b3  = (const float*)d_in[13];
    // d_in[14] = ref_length (int, == 128): fixed at compile time.

    // ws layout (floats): arrs [0,1024), y1 [1024,1280).
    float* arrs = (float*)d_ws;
    float* y1   = arrs + 1024;

    side_kernel<<<dim3(256), dim3(512), 0, stream>>>(points_c, trans, ref_feats,
                                                     src_feats, W1, arrs);
    mlp1_kernel<<<dim3(256), dim3(256), 0, stream>>>(arrs, W1, b1, W2,
                                                     g1, bt1, W3, b2, g2, bt2, y1);
    tail_kernel<<<dim3(1), dim3(512), 0, stream>>>(y1, g1, bt1, W2, b2,
                                                   g2, bt2, W3, b3, (float*)d_out);
}